// Round 14
// baseline (534.530 us; speedup 1.0000x reference)
//
#include <hip/hip_runtime.h>
#include <cstddef>

#define Bn 256
#define Hd 128
#define Nd 2048
#define K3 384     // W row stride (3H)
#define NT 64      // n-tile

typedef _Float16 half8 __attribute__((ext_vector_type(8)));
typedef float    float4v __attribute__((ext_vector_type(4)));

#define SFENCE() __builtin_amdgcn_sched_barrier(0)

__device__ __forceinline__ float fast_tanh(float x) {
    // tanh(x) = 1 - 2/(exp(2x)+1); saturates correctly at +/-inf
    return 1.0f - __fdividef(2.0f, __expf(2.0f * x) + 1.0f);
}

// ---------------------------------------------------------------------------
// prep 1: Wf[h][k] = fp16(W[h][k]) for k<256  (static+dynamic columns)
__global__ void prep_w16(const float* __restrict__ W, _Float16* __restrict__ Wf) {
    int idx = blockIdx.x * 256 + threadIdx.x;   // 0..32767
    int h = idx >> 8, k = idx & 255;
    Wf[idx] = (_Float16)W[h * K3 + k];
}

// prep 2: c[b][h] = sum_k W[h][256+k] * dec[b][k]  (decoder term, fp32 exact)
__global__ void prep_c(const float* __restrict__ W, const float* __restrict__ dec,
                       float* __restrict__ cb) {
    __shared__ float dl[Hd];
    int b = blockIdx.x;
    int h = threadIdx.x;       // 128 threads
    dl[h] = dec[b * Hd + h];
    __syncthreads();
    float acc = 0.f;
    #pragma unroll 8
    for (int k = 0; k < Hd; ++k)
        acc = fmaf(W[h * K3 + 256 + k], dl[k], acc);
    cb[b * Hd + h] = acc;
}

// ---------------------------------------------------------------------------
// Main: R9/R12 overlap schedule at 4 BLOCKS/CU (high occupancy x deep
// bursts x load-under-MFMA overlap -- the untested combination).
// R13 post-mortem: core dump from an ADDRESS BUG -- the dyn global read
// had a spurious +128 row offset (belongs only in the LDS chunk index,
// ck=16+...; dhp has 128 rows/b => OOB at b=255, wrong data otherwise).
// Fixed here: dyn global rows = 32w+8qd+j (0..127), identical to R12's
// validated addressing. Theory unchanged:
// R2 = occupancy w/o outstanding loads slow; R9/R12 = overlap at 2
// blocks/CU -> ~170us score = 12.3 GB/s/CU, under the ~20KB/CU BW-latency
// product. This: 64-n tile, LDS 33KB -> 4 blocks/CU = 16 waves
// (launch_bounds(256,4), VGPR cap 128).
//
// VGPR fit: A-frags HALF-resident -- A[kt0-3] loaded BEFORE the dyn burst
// (older => its wait doesn't drain the burst), A[kt4-7] after sync2.
// v loaded in epilogue. Peak ~ acc(32)+A(32)+t(32)+Bf+addr ~ 125 < 128.
//
// Staging map (64n): lane (ln=lane&15, qd=lane>>4); instr j reads row
// kb+8qd+j, cols n0+4ln (quarter-wave = 256B contiguous segment); lane's
// 8 loads = 8 contiguous k -> 4 half8 swizzled writes (chunk ck, n=4ln+r,
// phys ck^((n>>1)&7)). Wave w: static rows kb=32w -> ck=4w+qd (0..15);
// dyn rows kb=32w of dhp -> ck=16+4w+qd (16..31). LDS content + MFMA read
// algebra IDENTICAL to R12 => bit-identical numerics (absmax 7.63e-6).
// Non-persistent (replay-safe class).
__global__ __launch_bounds__(256, 4)
void score_kernel(const float* __restrict__ shp, const float* __restrict__ dhp,
                  const _Float16* __restrict__ Wf, const float* __restrict__ cbp,
                  const float* __restrict__ v, float* __restrict__ out) {
    __shared__ __align__(16) _Float16 xl[NT * 256];   // 32 KB, swizzled
    __shared__ float red[4 * NT];                     // 1 KB

    const int tid  = threadIdx.x;
    const int w    = __builtin_amdgcn_readfirstlane(tid >> 6);  // wave id (SGPR)
    const int lane = tid & 63;
    const int qd   = lane >> 4;       // quad 0..3 (also k sub-band for staging)
    const int ln   = lane & 15;       // (also n group for staging)
    const int b    = blockIdx.y;
    const int n0   = blockIdx.x * NT;
    const int h0   = w * 32;
    const size_t bstr = (size_t)Hd * Nd;

    // ---- acc init with decoder term: D row = quad*4 + reg
    float4v acc[2][4];
    {
        float4v c0 = *reinterpret_cast<const float4v*>(cbp + (size_t)b * Hd + h0 + qd * 4);
        float4v c1 = *reinterpret_cast<const float4v*>(cbp + (size_t)b * Hd + h0 + 16 + qd * 4);
        #pragma unroll
        for (int Nt = 0; Nt < 4; ++Nt) { acc[0][Nt] = c0; acc[1][Nt] = c1; }
    }

    // ---- A fragments kt0..3 (L2-hot Wf). A[m=ln][k=qd*8+j].
    half8 A[4][2];
    #pragma unroll
    for (int kt = 0; kt < 4; ++kt) {
        A[kt][0] = *reinterpret_cast<const half8*>(Wf + ((h0 + ln) << 8) + kt * 32 + qd * 8);
        A[kt][1] = *reinterpret_cast<const half8*>(Wf + ((h0 + 16 + ln) << 8) + kt * 32 + qd * 8);
    }

    // ---- prologue: stage static half (chunks 0..15)
    const float* sb = shp + (size_t)b * bstr + n0 + 4 * ln;
    const float* db = dhp + (size_t)b * bstr + n0 + 4 * ln;
    float4v t[8];
    {
        #pragma unroll
        for (int j = 0; j < 8; ++j)
            t[j] = *reinterpret_cast<const float4v*>(sb + (size_t)(32 * w + 8 * qd + j) * Nd);
        const int ck = 4 * w + qd;
        #pragma unroll
        for (int r = 0; r < 4; ++r) {
            const int n  = 4 * ln + r;
            const int sw = (n >> 1) & 7;
            half8 e;
            #pragma unroll
            for (int j = 0; j < 8; ++j) e[j] = (_Float16)t[j][r];
            *reinterpret_cast<half8*>(&xl[n * 256 + ((ck ^ sw) << 3)]) = e;
        }
    }
    __syncthreads();

    const int swr = (ln >> 1) & 7;

    // ---- issue dyn burst (rows 0..127 of dhp; stays in flight across kt0-3)
    SFENCE();
    #pragma unroll
    for (int j = 0; j < 8; ++j)
        t[j] = *reinterpret_cast<const float4v*>(db + (size_t)(32 * w + 8 * qd + j) * Nd);
    SFENCE();

    // ---- MFMA kt0-3 on static chunks
    #pragma unroll
    for (int kt = 0; kt < 4; ++kt) {
        const int ckb = kt * 4 + qd;
        #pragma unroll
        for (int Nt = 0; Nt < 4; ++Nt) {
            const int row = Nt * 16 + ln;
            half8 Bf = *reinterpret_cast<const half8*>(&xl[row * 256 + ((ckb ^ swr) << 3)]);
            acc[0][Nt] = __builtin_amdgcn_mfma_f32_16x16x32_f16(A[kt][0], Bf, acc[0][Nt], 0, 0, 0);
            acc[1][Nt] = __builtin_amdgcn_mfma_f32_16x16x32_f16(A[kt][1], Bf, acc[1][Nt], 0, 0, 0);
        }
    }
    SFENCE();

    // ---- cvt + swizzled write of dyn (chunks 16..31)
    {
        const int ck = 16 + 4 * w + qd;
        #pragma unroll
        for (int r = 0; r < 4; ++r) {
            const int n  = 4 * ln + r;
            const int sw = (n >> 1) & 7;
            half8 e;
            #pragma unroll
            for (int j = 0; j < 8; ++j) e[j] = (_Float16)t[j][r];
            *reinterpret_cast<half8*>(&xl[n * 256 + ((ck ^ sw) << 3)]) = e;
        }
    }
    __syncthreads();

    // ---- A fragments kt4..7 (reuse regs), MFMA kt4-7 on dyn chunks
    #pragma unroll
    for (int kt = 0; kt < 4; ++kt) {
        A[kt][0] = *reinterpret_cast<const half8*>(Wf + ((h0 + ln) << 8) + (kt + 4) * 32 + qd * 8);
        A[kt][1] = *reinterpret_cast<const half8*>(Wf + ((h0 + 16 + ln) << 8) + (kt + 4) * 32 + qd * 8);
    }
    #pragma unroll
    for (int kt = 0; kt < 4; ++kt) {
        const int ckb = (kt + 4) * 4 + qd;
        #pragma unroll
        for (int Nt = 0; Nt < 4; ++Nt) {
            const int row = Nt * 16 + ln;
            half8 Bf = *reinterpret_cast<const half8*>(&xl[row * 256 + ((ckb ^ swr) << 3)]);
            acc[0][Nt] = __builtin_amdgcn_mfma_f32_16x16x32_f16(A[kt][0], Bf, acc[0][Nt], 0, 0, 0);
            acc[1][Nt] = __builtin_amdgcn_mfma_f32_16x16x32_f16(A[kt][1], Bf, acc[1][Nt], 0, 0, 0);
        }
    }

    // ---- epilogue: score[n] = sum_m v[m] * tanh(t[m][n])
    const float4v v0 = *reinterpret_cast<const float4v*>(v + h0 + qd * 4);
    const float4v v1 = *reinterpret_cast<const float4v*>(v + h0 + 16 + qd * 4);
    #pragma unroll
    for (int Nt = 0; Nt < 4; ++Nt) {
        float part = 0.f;
        #pragma unroll
        for (int r = 0; r < 4; ++r) {
            part = fmaf(v0[r], fast_tanh(acc[0][Nt][r]), part);
            part = fmaf(v1[r], fast_tanh(acc[1][Nt][r]), part);
        }
        part += __shfl_xor(part, 16);   // sum quads (same n)
        part += __shfl_xor(part, 32);
        if (qd == 0) red[w * NT + Nt * 16 + ln] = part;
    }
    __syncthreads();
    if (tid < NT) {
        float s = red[tid] + red[NT + tid] + red[2 * NT + tid] + red[3 * NT + tid];
        out[(size_t)b * Nd + n0 + tid] = s;
    }
}

// ---------------------------------------------------------------------------
// softmax over n=2048 per b, in place. (validated round 1)
__global__ void softmax_k(float* __restrict__ out) {
    int b = blockIdx.x;
    float* row = out + (size_t)b * Nd;
    int tid = threadIdx.x;

    float loc[8];
    float mx = -3.4e38f;
    #pragma unroll
    for (int i = 0; i < 8; ++i) {
        loc[i] = row[tid + (i << 8)];
        mx = fmaxf(mx, loc[i]);
    }
    #pragma unroll
    for (int off = 32; off > 0; off >>= 1) mx = fmaxf(mx, __shfl_xor(mx, off));
    __shared__ float s4[4];
    if ((tid & 63) == 0) s4[tid >> 6] = mx;
    __syncthreads();
    mx = fmaxf(fmaxf(s4[0], s4[1]), fmaxf(s4[2], s4[3]));

    float sum = 0.f;
    #pragma unroll
    for (int i = 0; i < 8; ++i) {
        loc[i] = __expf(loc[i] - mx);
        sum += loc[i];
    }
    #pragma unroll
    for (int off = 32; off > 0; off >>= 1) sum += __shfl_xor(sum, off);
    __shared__ float s4b[4];
    if ((tid & 63) == 0) s4b[tid >> 6] = sum;
    __syncthreads();
    sum = s4b[0] + s4b[1] + s4b[2] + s4b[3];

    float inv = 1.0f / sum;
    #pragma unroll
    for (int i = 0; i < 8; ++i) row[tid + (i << 8)] = loc[i] * inv;
}

// ---------------------------------------------------------------------------
extern "C" void kernel_launch(void* const* d_in, const int* in_sizes, int n_in,
                              void* d_out, int out_size, void* d_ws, size_t ws_size,
                              hipStream_t stream) {
    const float* shp = (const float*)d_in[0];   // static_hidden [B,H,N]
    const float* dhp = (const float*)d_in[1];   // dynamic_hidden [B,H,N]
    const float* dec = (const float*)d_in[2];   // decoder_hidden [B,H]
    const float* v   = (const float*)d_in[3];   // [H]
    const float* W   = (const float*)d_in[4];   // [H, 3H]
    float* out = (float*)d_out;                 // [B,1,N]

    _Float16* Wf = (_Float16*)d_ws;             // 32768 halves = 64 KB
    float* cbp = (float*)((char*)d_ws + 65536); // 32768 floats = 128 KB

    hipLaunchKernelGGL(prep_w16, dim3(128), dim3(256), 0, stream, W, Wf);
    hipLaunchKernelGGL(prep_c,   dim3(Bn),  dim3(Hd),  0, stream, W, dec, cbp);
    hipLaunchKernelGGL(score_kernel, dim3(Nd / NT, Bn), dim3(256), 0, stream,
                       shp, dhp, Wf, cbp, v, out);
    hipLaunchKernelGGL(softmax_k, dim3(Bn), dim3(256), 0, stream, out);
}

// Round 15
// 518.699 us; speedup vs baseline: 1.0305x; 1.0305x over previous
//
#include <hip/hip_runtime.h>
#include <cstddef>

#define Bn 256
#define Hd 128
#define Nd 2048
#define K3 384     // W row stride (3H)

typedef _Float16 half8 __attribute__((ext_vector_type(8)));
typedef float    float4v __attribute__((ext_vector_type(4)));

#define SFENCE() __builtin_amdgcn_sched_barrier(0)

__device__ __forceinline__ float fast_tanh(float x) {
    // tanh(x) = 1 - 2/(exp(2x)+1); saturates correctly at +/-inf
    return 1.0f - __fdividef(2.0f, __expf(2.0f * x) + 1.0f);
}

// ---------------------------------------------------------------------------
// prep 1: Wf[h][k] = fp16(W[h][k]) for k<256  (static+dynamic columns)
__global__ void prep_w16(const float* __restrict__ W, _Float16* __restrict__ Wf) {
    int idx = blockIdx.x * 256 + threadIdx.x;   // 0..32767
    int h = idx >> 8, k = idx & 255;
    Wf[idx] = (_Float16)W[h * K3 + k];
}

// prep 2: c[b][h] = sum_k W[h][256+k] * dec[b][k]  (decoder term, fp32 exact)
__global__ void prep_c(const float* __restrict__ W, const float* __restrict__ dec,
                       float* __restrict__ cb) {
    __shared__ float dl[Hd];
    int b = blockIdx.x;
    int h = threadIdx.x;       // 128 threads
    dl[h] = dec[b * Hd + h];
    __syncthreads();
    float acc = 0.f;
    #pragma unroll 8
    for (int k = 0; k < Hd; ++k)
        acc = fmaf(W[h * K3 + 256 + k], dl[k], acc);
    cb[b * Hd + h] = acc;
}

// ---------------------------------------------------------------------------
// Main: R9 (session best, 512.9us total) with the STATIC half pipelined too.
// Evidence: R9 hid dyn loads under kt0-3 (+6us); static 64KB/block stayed
// serial. R14 disproved occupancy as a lever (39% occ -> 175us, worse);
// empirical optimum is this family: 2 blocks/CU, 128-n tile, big bursts.
//
// 5-phase schedule (chunk ranges disjoint from concurrently-read ones):
//  prologue: A-frags, acc-init, stage static k0-63  (chunks 0-7)   sync
//  P1: issue static k64-127 | MFMA kt0,1 (rd 0-7)  | wr chunks 8-15  sync
//  P2: issue dyn    k0-63   | MFMA kt2,3 (rd 8-15) | wr chunks 16-23 sync
//  P3: issue dyn    k64-127 | MFMA kt4,5 (rd16-23) | wr chunks 24-31 sync
//  P4: MFMA kt6,7 (rd 24-31) | epilogue | red sync | out
// Cold serial stall halves (64KB -> 32KB/block). MFMA order kt0..7 and all
// staging/swizzle algebra IDENTICAL to R9 => bit-identical numerics
// (absmax 7.63e-6). Non-persistent (replay-safe class).
//
// block = (b, 128-n tile), 256 thr = 4 waves, 2 blocks/CU (66 KB LDS).
// Wave w: h in [32w,32w+32) (2 M-tiles), all 128 n (8 N-tiles), acc[2][8].
// Staging burst: kl rows kl..kl+7 per wave, lane covers n1=2*lane,n1+1;
// LDS [n][k] fp16, 16B-chunk XOR swizzle p = ck ^ ((n>>1)&7).
__global__ __launch_bounds__(256, 2)
void score_kernel(const float* __restrict__ shp, const float* __restrict__ dhp,
                  const _Float16* __restrict__ Wf, const float* __restrict__ cbp,
                  const float* __restrict__ v, float* __restrict__ out) {
    __shared__ __align__(16) _Float16 xl[128 * 256];   // 64 KB, swizzled
    __shared__ float red[4 * 128];

    const int tid  = threadIdx.x;
    const int w    = __builtin_amdgcn_readfirstlane(tid >> 6);  // wave id (SGPR)
    const int lane = tid & 63;
    const int qd   = lane >> 4;       // quad 0..3
    const int ln   = lane & 15;
    const int b    = blockIdx.y;
    const int n0   = blockIdx.x * 128;
    const int h0   = w * 32;

    // ---- A fragments (W) -> registers. A[m=lane&15][k=quad*8+j].
    half8 Af[2][8];
    #pragma unroll
    for (int Mt = 0; Mt < 2; ++Mt) {
        const _Float16* wp = Wf + ((h0 + Mt * 16 + ln) << 8) + qd * 8;
        #pragma unroll
        for (int kt = 0; kt < 8; ++kt)
            Af[Mt][kt] = *reinterpret_cast<const half8*>(wp + kt * 32);
    }

    // ---- acc init with decoder term: D row = quad*4 + reg
    float4v acc[2][8];
    #pragma unroll
    for (int Mt = 0; Mt < 2; ++Mt) {
        float4v c4 = *reinterpret_cast<const float4v*>(cbp + b * Hd + h0 + Mt * 16 + qd * 4);
        #pragma unroll
        for (int Nt = 0; Nt < 8; ++Nt) acc[Mt][Nt] = c4;
    }

    // ---- staging constants: lane covers n1, n1+1 for an 8-row k band per burst
    const int n1  = 2 * lane;        // even row
    const int swz = lane & 7;        // ((n1>>1)&7) == ((n1+1)>>1)&7
    const int swr = (ln >> 1) & 7;
    const size_t bofs = (size_t)b * (Hd * (size_t)Nd) + n0 + n1;
    const float* ssrc = shp + bofs;
    const float* dsrc = dhp + bofs;

    // ---- prologue: stage static k0-63 (chunks 0..7)
    #pragma unroll
    for (int i = 0; i < 2; ++i) {
        const int kl = i * 32 + w * 8;
        float2 xv[8];
        #pragma unroll
        for (int j = 0; j < 8; ++j)
            xv[j] = *reinterpret_cast<const float2*>(ssrc + (size_t)(kl + j) * Nd);
        half8 e0, e1;
        #pragma unroll
        for (int j = 0; j < 8; ++j) {
            e0[j] = (_Float16)xv[j].x;
            e1[j] = (_Float16)xv[j].y;
        }
        const int p = (kl >> 3) ^ swz;
        *reinterpret_cast<half8*>(&xl[n1 * 256 + p * 8])       = e0;
        *reinterpret_cast<half8*>(&xl[(n1 + 1) * 256 + p * 8]) = e1;
    }
    __syncthreads();

    // ---- P1..P3: {issue loads | MFMA kt pair | cvt+write}  (see header map)
    #pragma unroll
    for (int ph = 0; ph < 3; ++ph) {
        // load source + logical k-row base + chunk base for this phase
        const float* src = (ph == 0) ? ssrc : dsrc;
        const int klb    = (ph == 0) ? 64 : (ph == 1) ? 0 : 64;   // row base
        const int ckbase = 8 + 8 * ph;                            // chunks written

        float2 yv[2][8];
        #pragma unroll
        for (int i2 = 0; i2 < 2; ++i2) {
            const int kl = klb + i2 * 32 + w * 8;
            #pragma unroll
            for (int j = 0; j < 8; ++j)
                yv[i2][j] = *reinterpret_cast<const float2*>(src + (size_t)(kl + j) * Nd);
        }
        SFENCE();   // pin load issue above the MFMA cluster

        // MFMA kt = 2ph, 2ph+1 (reads chunks 8ph-7.. = staged 2 phases ago)
        #pragma unroll
        for (int kt = 2 * ph; kt < 2 * ph + 2; ++kt) {
            half8 Bf[8];
            const int ckb = kt * 4 + qd;
            #pragma unroll
            for (int Nt = 0; Nt < 8; ++Nt) {
                const int row = Nt * 16 + ln;
                Bf[Nt] = *reinterpret_cast<const half8*>(&xl[row * 256 + ((ckb ^ swr) << 3)]);
            }
            #pragma unroll
            for (int Nt = 0; Nt < 8; ++Nt) {
                acc[0][Nt] = __builtin_amdgcn_mfma_f32_16x16x32_f16(Af[0][kt], Bf[Nt], acc[0][Nt], 0, 0, 0);
                acc[1][Nt] = __builtin_amdgcn_mfma_f32_16x16x32_f16(Af[1][kt], Bf[Nt], acc[1][Nt], 0, 0, 0);
            }
        }
        SFENCE();

        // cvt + swizzled write (chunks ckbase .. ckbase+7)
        #pragma unroll
        for (int i2 = 0; i2 < 2; ++i2) {
            const int kl = klb + i2 * 32 + w * 8;
            half8 e0, e1;
            #pragma unroll
            for (int j = 0; j < 8; ++j) {
                e0[j] = (_Float16)yv[i2][j].x;
                e1[j] = (_Float16)yv[i2][j].y;
            }
            const int p = (ckbase + ((kl - klb) >> 3)) ^ swz;   // = ckbase + 4*i2 + w
            *reinterpret_cast<half8*>(&xl[n1 * 256 + p * 8])       = e0;
            *reinterpret_cast<half8*>(&xl[(n1 + 1) * 256 + p * 8]) = e1;
        }
        __syncthreads();
    }

    // ---- P4: MFMA kt6,7 on chunks 24-31
    #pragma unroll
    for (int kt = 6; kt < 8; ++kt) {
        half8 Bf[8];
        const int ckb = kt * 4 + qd;
        #pragma unroll
        for (int Nt = 0; Nt < 8; ++Nt) {
            const int row = Nt * 16 + ln;
            Bf[Nt] = *reinterpret_cast<const half8*>(&xl[row * 256 + ((ckb ^ swr) << 3)]);
        }
        #pragma unroll
        for (int Nt = 0; Nt < 8; ++Nt) {
            acc[0][Nt] = __builtin_amdgcn_mfma_f32_16x16x32_f16(Af[0][kt], Bf[Nt], acc[0][Nt], 0, 0, 0);
            acc[1][Nt] = __builtin_amdgcn_mfma_f32_16x16x32_f16(Af[1][kt], Bf[Nt], acc[1][Nt], 0, 0, 0);
        }
    }

    // ---- epilogue: score[n] = sum_m v[m] * tanh(t[m][n])
    float4v v0 = *reinterpret_cast<const float4v*>(v + h0 + qd * 4);
    float4v v1 = *reinterpret_cast<const float4v*>(v + h0 + 16 + qd * 4);
    #pragma unroll
    for (int Nt = 0; Nt < 8; ++Nt) {
        float part = 0.f;
        #pragma unroll
        for (int r = 0; r < 4; ++r) {
            part = fmaf(v0[r], fast_tanh(acc[0][Nt][r]), part);
            part = fmaf(v1[r], fast_tanh(acc[1][Nt][r]), part);
        }
        part += __shfl_xor(part, 16);   // sum quads (same n)
        part += __shfl_xor(part, 32);
        if (qd == 0) red[w * 128 + Nt * 16 + ln] = part;
    }
    __syncthreads();
    if (tid < 128) {
        float s = red[tid] + red[128 + tid] + red[256 + tid] + red[384 + tid];
        out[(size_t)b * Nd + n0 + tid] = s;
    }
}

// ---------------------------------------------------------------------------
// softmax over n=2048 per b, in place. (validated round 1)
__global__ void softmax_k(float* __restrict__ out) {
    int b = blockIdx.x;
    float* row = out + (size_t)b * Nd;
    int tid = threadIdx.x;

    float loc[8];
    float mx = -3.4e38f;
    #pragma unroll
    for (int i = 0; i < 8; ++i) {
        loc[i] = row[tid + (i << 8)];
        mx = fmaxf(mx, loc[i]);
    }
    #pragma unroll
    for (int off = 32; off > 0; off >>= 1) mx = fmaxf(mx, __shfl_xor(mx, off));
    __shared__ float s4[4];
    if ((tid & 63) == 0) s4[tid >> 6] = mx;
    __syncthreads();
    mx = fmaxf(fmaxf(s4[0], s4[1]), fmaxf(s4[2], s4[3]));

    float sum = 0.f;
    #pragma unroll
    for (int i = 0; i < 8; ++i) {
        loc[i] = __expf(loc[i] - mx);
        sum += loc[i];
    }
    #pragma unroll
    for (int off = 32; off > 0; off >>= 1) sum += __shfl_xor(sum, off);
    __shared__ float s4b[4];
    if ((tid & 63) == 0) s4b[tid >> 6] = sum;
    __syncthreads();
    sum = s4b[0] + s4b[1] + s4b[2] + s4b[3];

    float inv = 1.0f / sum;
    #pragma unroll
    for (int i = 0; i < 8; ++i) row[tid + (i << 8)] = loc[i] * inv;
}

// ---------------------------------------------------------------------------
extern "C" void kernel_launch(void* const* d_in, const int* in_sizes, int n_in,
                              void* d_out, int out_size, void* d_ws, size_t ws_size,
                              hipStream_t stream) {
    const float* shp = (const float*)d_in[0];   // static_hidden [B,H,N]
    const float* dhp = (const float*)d_in[1];   // dynamic_hidden [B,H,N]
    const float* dec = (const float*)d_in[2];   // decoder_hidden [B,H]
    const float* v   = (const float*)d_in[3];   // [H]
    const float* W   = (const float*)d_in[4];   // [H, 3H]
    float* out = (float*)d_out;                 // [B,1,N]

    _Float16* Wf = (_Float16*)d_ws;             // 32768 halves = 64 KB
    float* cbp = (float*)((char*)d_ws + 65536); // 32768 floats = 128 KB

    hipLaunchKernelGGL(prep_w16, dim3(128), dim3(256), 0, stream, W, Wf);
    hipLaunchKernelGGL(prep_c,   dim3(Bn),  dim3(Hd),  0, stream, W, dec, cbp);
    hipLaunchKernelGGL(score_kernel, dim3(Nd / 128, Bn), dim3(256), 0, stream,
                       shp, dhp, Wf, cbp, v, out);
    hipLaunchKernelGGL(softmax_k, dim3(Bn), dim3(256), 0, stream, out);
}

// Round 16
// 517.383 us; speedup vs baseline: 1.0331x; 1.0025x over previous
//
#include <hip/hip_runtime.h>
#include <cstddef>

#define Bn 256
#define Hd 128
#define Nd 2048
#define K3 384     // W row stride (3H)

typedef _Float16 half8 __attribute__((ext_vector_type(8)));
typedef float    float4v __attribute__((ext_vector_type(4)));

#define SFENCE() __builtin_amdgcn_sched_barrier(0)

__device__ __forceinline__ float fast_tanh(float x) {
    // tanh(x) = 1 - 2/(exp(2x)+1); saturates correctly at +/-inf
    return 1.0f - __fdividef(2.0f, __expf(2.0f * x) + 1.0f);
}

// ---------------------------------------------------------------------------
// prep 1: Wf[h][k] = fp16(W[h][k]) for k<256  (static+dynamic columns)
__global__ void prep_w16(const float* __restrict__ W, _Float16* __restrict__ Wf) {
    int idx = blockIdx.x * 256 + threadIdx.x;   // 0..32767
    int h = idx >> 8, k = idx & 255;
    Wf[idx] = (_Float16)W[h * K3 + k];
}

// prep 2: c[b][h] = sum_k W[h][256+k] * dec[b][k]  (decoder term, fp32 exact)
__global__ void prep_c(const float* __restrict__ W, const float* __restrict__ dec,
                       float* __restrict__ cb) {
    __shared__ float dl[Hd];
    int b = blockIdx.x;
    int h = threadIdx.x;       // 128 threads
    dl[h] = dec[b * Hd + h];
    __syncthreads();
    float acc = 0.f;
    #pragma unroll 8
    for (int k = 0; k < Hd; ++k)
        acc = fmaf(W[h * K3 + 256 + k], dl[k], acc);
    cb[b * Hd + h] = acc;
}

// ---------------------------------------------------------------------------
// FINAL STATE: best verified kernel of the session (benched round 9:
// 512.87us total, score ~150us) -- restored bit-for-bit.
//
// Session evidence (R0-R15): logical read rate pins at ~12-13 GB/s/CU
// across register bursts, DMA (drained/counted/64KB-deep), 1KB segments,
// occupancy 20-79%, persistence, wave specialization. Only win: hiding the
// dyn-half loads under the static-half MFMA (this kernel, +~40us total).
// Deeper pipelining (R15) and occupancy (R14) cost a few us each.
// Persistence (R7/R11) intermittently diverges under graph replay: closed.
// Remainder of total is harness re-poison fills at 84% HBM peak.
//
// block = (b, 128-n tile), 256 threads = 4 waves, 2 blocks/CU (66 KB LDS).
// Wave w owns h in [32w,32w+32) (2 M-tiles); all waves share 128 n (8
// N-tiles), acc[2][8], K=256 via 16x16x32 MFMA. W A-frags resident (L2-hot
// Wf). x staged to LDS fp16 [n][k], 16B-chunk XOR swizzle p = ck^((n>>1)&7).
//
// Schedule: stage static (chunks 0..15) -> sync ->
//   { hp=0: issue 16 dyn float2 loads | MFMA kt0,1 | cvt+write dyn i2={0,1} }
//   { hp=1: same for kt2,3 / i2={2,3} } -> sync -> MFMA kt4..7 -> epilogue.
// sched_barrier pins load-issue above the MFMA cluster; the compiler's
// vmcnt wait lands at the cvt (first use), so dyn-load latency hides under
// MFMA + ds_read work.
__global__ __launch_bounds__(256, 2)
void score_kernel(const float* __restrict__ shp, const float* __restrict__ dhp,
                  const _Float16* __restrict__ Wf, const float* __restrict__ cbp,
                  const float* __restrict__ v, float* __restrict__ out) {
    __shared__ __align__(16) _Float16 xl[128 * 256];   // 64 KB, swizzled
    __shared__ float red[4 * 128];

    const int tid  = threadIdx.x;
    const int w    = __builtin_amdgcn_readfirstlane(tid >> 6);  // wave id (SGPR)
    const int lane = tid & 63;
    const int qd   = lane >> 4;       // quad 0..3
    const int ln   = lane & 15;
    const int b    = blockIdx.y;
    const int n0   = blockIdx.x * 128;
    const int h0   = w * 32;

    // ---- A fragments (W) -> registers. A[m=lane&15][k=quad*8+j].
    half8 Af[2][8];
    #pragma unroll
    for (int Mt = 0; Mt < 2; ++Mt) {
        const _Float16* wp = Wf + ((h0 + Mt * 16 + ln) << 8) + qd * 8;
        #pragma unroll
        for (int kt = 0; kt < 8; ++kt)
            Af[Mt][kt] = *reinterpret_cast<const half8*>(wp + kt * 32);
    }

    // ---- acc init with decoder term: D row = quad*4 + reg
    float4v acc[2][8];
    #pragma unroll
    for (int Mt = 0; Mt < 2; ++Mt) {
        float4v c4 = *reinterpret_cast<const float4v*>(cbp + b * Hd + h0 + Mt * 16 + qd * 4);
        #pragma unroll
        for (int Nt = 0; Nt < 8; ++Nt) acc[Mt][Nt] = c4;
    }

    // ---- staging constants: lane covers n1, n1+1 for a 8-row k band per i
    const int n1  = 2 * lane;        // even row
    const int swz = lane & 7;        // ((n1>>1)&7) == ((n1+1)>>1)&7
    const size_t bofs = (size_t)b * (Hd * (size_t)Nd) + n0 + n1;

    // ---- phase A: stage static half (logical chunks 0..15)
    {
        const float* src = shp + bofs;
        #pragma unroll
        for (int i = 0; i < 4; ++i) {
            const int kl = i * 32 + w * 8;          // wave-uniform, 0..120
            float2 xv[8];
            #pragma unroll
            for (int j = 0; j < 8; ++j)
                xv[j] = *reinterpret_cast<const float2*>(src + (size_t)(kl + j) * Nd);
            half8 e0, e1;
            #pragma unroll
            for (int j = 0; j < 8; ++j) {
                e0[j] = (_Float16)xv[j].x;
                e1[j] = (_Float16)xv[j].y;
            }
            const int p = (kl >> 3) ^ swz;
            *reinterpret_cast<half8*>(&xl[n1 * 256 + p * 8])       = e0;
            *reinterpret_cast<half8*>(&xl[(n1 + 1) * 256 + p * 8]) = e1;
        }
    }
    __syncthreads();

    const int swr = (ln >> 1) & 7;
    const float* dsrc = dhp + bofs;

    // ---- phase B: overlap dynamic staging with static-half MFMA
    #pragma unroll
    for (int hp = 0; hp < 2; ++hp) {
        // issue 16 dynamic loads (k rows for i2 = 2hp, 2hp+1)
        float2 yv[2][8];
        #pragma unroll
        for (int i2 = 0; i2 < 2; ++i2) {
            const int kl = (2 * hp + i2) * 32 + w * 8;
            #pragma unroll
            for (int j = 0; j < 8; ++j)
                yv[i2][j] = *reinterpret_cast<const float2*>(dsrc + (size_t)(kl + j) * Nd);
        }
        SFENCE();   // pin load issue above the MFMA cluster

        // MFMA on static chunks: kt = 2hp, 2hp+1 (ckb <= 15)
        #pragma unroll
        for (int kt = 2 * hp; kt < 2 * hp + 2; ++kt) {
            half8 Bf[8];
            const int ckb = kt * 4 + qd;
            #pragma unroll
            for (int Nt = 0; Nt < 8; ++Nt) {
                const int row = Nt * 16 + ln;
                Bf[Nt] = *reinterpret_cast<const half8*>(&xl[row * 256 + ((ckb ^ swr) << 3)]);
            }
            #pragma unroll
            for (int Nt = 0; Nt < 8; ++Nt) {
                acc[0][Nt] = __builtin_amdgcn_mfma_f32_16x16x32_f16(Af[0][kt], Bf[Nt], acc[0][Nt], 0, 0, 0);
                acc[1][Nt] = __builtin_amdgcn_mfma_f32_16x16x32_f16(Af[1][kt], Bf[Nt], acc[1][Nt], 0, 0, 0);
            }
        }
        SFENCE();

        // cvt + swizzled write of the dynamic rows (chunks 16..31)
        #pragma unroll
        for (int i2 = 0; i2 < 2; ++i2) {
            const int kl = (2 * hp + i2) * 32 + w * 8;
            half8 e0, e1;
            #pragma unroll
            for (int j = 0; j < 8; ++j) {
                e0[j] = (_Float16)yv[i2][j].x;
                e1[j] = (_Float16)yv[i2][j].y;
            }
            const int p = ((128 + kl) >> 3) ^ swz;
            *reinterpret_cast<half8*>(&xl[n1 * 256 + p * 8])       = e0;
            *reinterpret_cast<half8*>(&xl[(n1 + 1) * 256 + p * 8]) = e1;
        }
    }
    __syncthreads();

    // ---- MFMA on dynamic chunks: kt 4..7
    #pragma unroll
    for (int kt = 4; kt < 8; ++kt) {
        half8 Bf[8];
        const int ckb = kt * 4 + qd;
        #pragma unroll
        for (int Nt = 0; Nt < 8; ++Nt) {
            const int row = Nt * 16 + ln;
            Bf[Nt] = *reinterpret_cast<const half8*>(&xl[row * 256 + ((ckb ^ swr) << 3)]);
        }
        #pragma unroll
        for (int Nt = 0; Nt < 8; ++Nt) {
            acc[0][Nt] = __builtin_amdgcn_mfma_f32_16x16x32_f16(Af[0][kt], Bf[Nt], acc[0][Nt], 0, 0, 0);
            acc[1][Nt] = __builtin_amdgcn_mfma_f32_16x16x32_f16(Af[1][kt], Bf[Nt], acc[1][Nt], 0, 0, 0);
        }
    }

    // ---- epilogue: score[n] = sum_m v[m] * tanh(t[m][n])
    float4v v0 = *reinterpret_cast<const float4v*>(v + h0 + qd * 4);
    float4v v1 = *reinterpret_cast<const float4v*>(v + h0 + 16 + qd * 4);
    #pragma unroll
    for (int Nt = 0; Nt < 8; ++Nt) {
        float part = 0.f;
        #pragma unroll
        for (int r = 0; r < 4; ++r) {
            part = fmaf(v0[r], fast_tanh(acc[0][Nt][r]), part);
            part = fmaf(v1[r], fast_tanh(acc[1][Nt][r]), part);
        }
        part += __shfl_xor(part, 16);   // sum quads (same n)
        part += __shfl_xor(part, 32);
        if (qd == 0) red[w * 128 + Nt * 16 + ln] = part;
    }
    __syncthreads();
    if (tid < 128) {
        float s = red[tid] + red[128 + tid] + red[256 + tid] + red[384 + tid];
        out[(size_t)b * Nd + n0 + tid] = s;
    }
}

// ---------------------------------------------------------------------------
// softmax over n=2048 per b, in place. (validated round 1)
__global__ void softmax_k(float* __restrict__ out) {
    int b = blockIdx.x;
    float* row = out + (size_t)b * Nd;
    int tid = threadIdx.x;

    float loc[8];
    float mx = -3.4e38f;
    #pragma unroll
    for (int i = 0; i < 8; ++i) {
        loc[i] = row[tid + (i << 8)];
        mx = fmaxf(mx, loc[i]);
    }
    #pragma unroll
    for (int off = 32; off > 0; off >>= 1) mx = fmaxf(mx, __shfl_xor(mx, off));
    __shared__ float s4[4];
    if ((tid & 63) == 0) s4[tid >> 6] = mx;
    __syncthreads();
    mx = fmaxf(fmaxf(s4[0], s4[1]), fmaxf(s4[2], s4[3]));

    float sum = 0.f;
    #pragma unroll
    for (int i = 0; i < 8; ++i) {
        loc[i] = __expf(loc[i] - mx);
        sum += loc[i];
    }
    #pragma unroll
    for (int off = 32; off > 0; off >>= 1) sum += __shfl_xor(sum, off);
    __shared__ float s4b[4];
    if ((tid & 63) == 0) s4b[tid >> 6] = sum;
    __syncthreads();
    sum = s4b[0] + s4b[1] + s4b[2] + s4b[3];

    float inv = 1.0f / sum;
    #pragma unroll
    for (int i = 0; i < 8; ++i) row[tid + (i << 8)] = loc[i] * inv;
}

// ---------------------------------------------------------------------------
extern "C" void kernel_launch(void* const* d_in, const int* in_sizes, int n_in,
                              void* d_out, int out_size, void* d_ws, size_t ws_size,
                              hipStream_t stream) {
    const float* shp = (const float*)d_in[0];   // static_hidden [B,H,N]
    const float* dhp = (const float*)d_in[1];   // dynamic_hidden [B,H,N]
    const float* dec = (const float*)d_in[2];   // decoder_hidden [B,H]
    const float* v   = (const float*)d_in[3];   // [H]
    const float* W   = (const float*)d_in[4];   // [H, 3H]
    float* out = (float*)d_out;                 // [B,1,N]

    _Float16* Wf = (_Float16*)d_ws;             // 32768 halves = 64 KB
    float* cbp = (float*)((char*)d_ws + 65536); // 32768 floats = 128 KB

    hipLaunchKernelGGL(prep_w16, dim3(128), dim3(256), 0, stream, W, Wf);
    hipLaunchKernelGGL(prep_c,   dim3(Bn),  dim3(Hd),  0, stream, W, dec, cbp);
    hipLaunchKernelGGL(score_kernel, dim3(Nd / 128, Bn), dim3(256), 0, stream,
                       shp, dhp, Wf, cbp, v, out);
    hipLaunchKernelGGL(softmax_k, dim3(Bn), dim3(256), 0, stream, out);
}